// Round 5
// baseline (421.255 us; speedup 1.0000x reference)
//
#include <hip/hip_runtime.h>
#include <hip/hip_bf16.h>
#include <math.h>

// Problem constants
#define BB 4
#define NN 1024
#define DD 256
#define CC 8
#define KNBR 16
#define MAXSEL 17   // 16 top-k + possibly the diagonal
#define ZCAP (NN * MAXSEL)   // 17408 max CSR entries per z

typedef _Float16 f16x8_t __attribute__((ext_vector_type(8)));
typedef _Float16 f16x4_t __attribute__((ext_vector_type(4)));
typedef float    f32x4_t __attribute__((ext_vector_type(4)));

// async global->LDS, 16 bytes per lane. ldsbase must be wave-uniform
// (HW places lane i at ldsbase + i*16).
__device__ __forceinline__ void gl2lds16(const _Float16* g, _Float16* ldsbase) {
    __builtin_amdgcn_global_load_lds(
        (const __attribute__((address_space(1))) unsigned int*)g,
        (__attribute__((address_space(3))) unsigned int*)ldsbase, 16, 0, 0);
}

// 2-level fp16 split: v = h + l + eps, |eps| <= ~2^-23 |v|
__device__ __forceinline__ void split2(float v, _Float16& h, _Float16& l) {
    h = (_Float16)v;
    l = (_Float16)(v - (float)h);
}

// ---------------------------------------------------------------------------
// Kernel 0: fused input prep. Blocks 0..1023: split x (fp16 h+l).
// Blocks 1024..1279: transpose + split 16*W (scale keeps residuals out of
// fp16 subnormal range; compensated by qkt scale /256).
// Block 1024 also zeroes countb.
// ---------------------------------------------------------------------------
__global__ __launch_bounds__(256) void split_all(const float* __restrict__ x,
                                                 const float* __restrict__ W,
                                                 _Float16* __restrict__ xh,
                                                 _Float16* __restrict__ xl,
                                                 _Float16* __restrict__ Wth,
                                                 _Float16* __restrict__ Wtl,
                                                 int* __restrict__ countb) {
    const int tid = threadIdx.x;
    if (blockIdx.x < 1024) {
        int i = (blockIdx.x * 256 + tid) * 4;
        float4 v = *(const float4*)(x + i);
        f16x4_t hv, lv;
        _Float16 h, l;
        split2(v.x, h, l); hv[0] = h; lv[0] = l;
        split2(v.y, h, l); hv[1] = h; lv[1] = l;
        split2(v.z, h, l); hv[2] = h; lv[2] = l;
        split2(v.w, h, l); hv[3] = h; lv[3] = l;
        *(f16x4_t*)(xh + i) = hv;
        *(f16x4_t*)(xl + i) = lv;
    } else {
        const int b2 = blockIdx.x - 1024;
        if (b2 == 0) {
            int4 zz = make_int4(0, 0, 0, 0);
#pragma unroll
            for (int g = 0; g < 4; g++) ((int4*)countb)[tid + 256 * g] = zz;
        }
        __shared__ float t[64][65];
        const int n0 = (b2 & 63) * 64;
        const int k0 = (b2 >> 6) * 64;
#pragma unroll
        for (int i = 0; i < 16; i++) {
            int k = i * 4 + (tid >> 6);
            int n = tid & 63;
            t[k][n] = W[(size_t)(k0 + k) * 4096 + n0 + n];
        }
        __syncthreads();
#pragma unroll
        for (int i = 0; i < 16; i++) {
            int n = i * 4 + (tid >> 6);
            int k = tid & 63;
            _Float16 h, l;
            split2(t[k][n] * 16.f, h, l);
            size_t o = (size_t)(n0 + n) * 256 + k0 + k;
            Wth[o] = h; Wtl[o] = l;
        }
    }
}

// stage one 128x32 fp16 tile.
// LDS dest is linear (HW constraint of global_load_lds); the bank-conflict
// swizzle slot' = slot ^ ((row>>1)&3) is realized by pre-swizzling the
// GLOBAL source column (c8 is the swizzled column offset; row = r_st and
// r_st+64 share the same (row>>1)&3 so one c8 serves both halves).
#define STG(dst, src, rowbase, kk)                                             \
    do {                                                                       \
        gl2lds16((src) + (size_t)((rowbase) + r_st) * 256 + (kk) + c8,         \
                 &(dst)[(w * 64) * 8]);                                        \
        gl2lds16((src) + (size_t)((rowbase) + 64 + r_st) * 256 + (kk) + c8,    \
                 &(dst)[(256 + w * 64) * 8]);                                  \
    } while (0)

// 3-term product ladder (hh last). (ah+al)(bh+bl) ~ al*bh + ah*bl + ah*bh
#define MFMA3(accv, AH, AL, BH, BL)                                            \
    do {                                                                       \
        accv = __builtin_amdgcn_mfma_f32_16x16x32_f16(AL, BH, accv, 0, 0, 0);  \
        accv = __builtin_amdgcn_mfma_f32_16x16x32_f16(AH, BL, accv, 0, 0, 0);  \
        accv = __builtin_amdgcn_mfma_f32_16x16x32_f16(AH, BH, accv, 0, 0, 0);  \
    } while (0)

// fragment loads + MFMA for one staged K=32 tile set
#define COMPUTE(AH, AL, BH, BL)                                                \
    do {                                                                       \
        f16x8_t ah[4], al[4];                                                  \
        _Pragma("unroll")                                                      \
        for (int mi = 0; mi < 4; mi++) {                                       \
            int r = (wr * 64 + mi * 16 + lm) * 32 + qx8;                       \
            ah[mi] = *(const f16x8_t*)&(AH)[r];                                \
            al[mi] = *(const f16x8_t*)&(AL)[r];                                \
        }                                                                      \
        _Pragma("unroll")                                                      \
        for (int ni = 0; ni < 4; ni++) {                                       \
            int rb = (wc * 64 + ni * 16 + lm) * 32 + qx8;                      \
            f16x8_t bh = *(const f16x8_t*)&(BH)[rb];                           \
            f16x8_t bl = *(const f16x8_t*)&(BL)[rb];                           \
            _Pragma("unroll")                                                  \
            for (int mi = 0; mi < 4; mi++)                                     \
                MFMA3(acc[mi][ni], ah[mi], al[mi], bh, bl);                    \
        }                                                                      \
    } while (0)

// ---------------------------------------------------------------------------
// Kernel 1: qk = x @ (16W) via 3-term fp16x2 MFMA, double-buffered LDS with
// next-tile prefetch (one barrier per K-iter); LDS-transpose epilogue with
// coalesced fp16x8 stores of the 2-split q/k components.
// ---------------------------------------------------------------------------
__global__ __launch_bounds__(256) void gemm_xw_mfma(
        const _Float16* __restrict__ xh, const _Float16* __restrict__ xl,
        const _Float16* __restrict__ wth, const _Float16* __restrict__ wtl,
        _Float16* __restrict__ qh, _Float16* __restrict__ ql,
        _Float16* __restrict__ kh, _Float16* __restrict__ kl) {
    __shared__ __align__(16) char smem[65536];
    _Float16* Ah0 = (_Float16*)smem;
    _Float16* Al0 = (_Float16*)(smem + 8192);
    _Float16* Bh0 = (_Float16*)(smem + 16384);
    _Float16* Bl0 = (_Float16*)(smem + 24576);
    _Float16* Ah1 = (_Float16*)(smem + 32768);
    _Float16* Al1 = (_Float16*)(smem + 40960);
    _Float16* Bh1 = (_Float16*)(smem + 49152);
    _Float16* Bl1 = (_Float16*)(smem + 57344);
    const int tid = threadIdx.x, lane = tid & 63, w = tid >> 6;
    const int wr = w >> 1, wc = w & 1;
    const int lm = lane & 15, quad = lane >> 4;
    const int row0 = blockIdx.y * 128, col0 = blockIdx.x * 128;
    const int r_st = tid >> 2;
    // swizzled source column: slot (tid&3) XOR row-swizzle ((r_st>>1)&3)
    const int c8 = (((tid & 3) ^ ((tid >> 3) & 3)) * 8);
    // swizzled read slot for fragment loads (row-base contributes 0 mod 4)
    const int qx8 = ((quad ^ ((lm >> 1) & 3)) * 8);

    f32x4_t acc[4][4];
#pragma unroll
    for (int i = 0; i < 4; i++)
#pragma unroll
        for (int j = 0; j < 4; j++) acc[i][j] = (f32x4_t)(0.f);

    // prologue: stage k=0 into buf0
    STG(Ah0, xh, row0, 0); STG(Al0, xl, row0, 0);
    STG(Bh0, wth, col0, 0); STG(Bl0, wtl, col0, 0);
    __syncthreads();
#pragma unroll
    for (int t = 0; t < 8; t += 2) {
        {   // even iter: compute buf0, prefetch (t+1) into buf1
            int kn = (t + 1) * 32;
            if (t + 1 < 8) {
                STG(Ah1, xh, row0, kn); STG(Al1, xl, row0, kn);
                STG(Bh1, wth, col0, kn); STG(Bl1, wtl, col0, kn);
            }
            COMPUTE(Ah0, Al0, Bh0, Bl0);
            __syncthreads();
        }
        {   // odd iter: compute buf1, prefetch (t+2) into buf0
            int kn = (t + 2) * 32;
            if (t + 2 < 8) {
                STG(Ah0, xh, row0, kn); STG(Al0, xl, row0, kn);
                STG(Bh0, wth, col0, kn); STG(Bl0, wtl, col0, kn);
            }
            COMPUTE(Ah1, Al1, Bh1, Bl1);
            __syncthreads();
        }
    }

    // Epilogue: two 64-row passes through LDS (fp32, stride 132 = bank-safe),
    // then coalesced fp16x8 stores of the 2 split components.
    float* tr = (float*)smem;   // 64 x 132 fp32 = 33792 B
    const int s = col0 >> 11, c = (col0 >> 8) & 7, dbase = col0 & 255;
    _Float16* dh = s ? kh : qh;
    _Float16* dl = s ? kl : ql;
    const int rl = tid >> 2;
    const int cb = (tid & 3) * 8;
#pragma unroll
    for (int p = 0; p < 2; p++) {
        if (p) __syncthreads();
        if (wr == p) {
#pragma unroll
            for (int mi = 0; mi < 4; mi++) {
                int rloc = mi * 16 + quad * 4;
#pragma unroll
                for (int ni = 0; ni < 4; ni++) {
                    int cl = wc * 64 + ni * 16 + lm;
#pragma unroll
                    for (int r = 0; r < 4; r++)
                        tr[(rloc + r) * 132 + cl] = acc[mi][ni][r];
                }
            }
        }
        __syncthreads();
        int rr = row0 + p * 64 + rl;
        int bb = rr >> 10, n = rr & 1023;
        size_t base = (((size_t)(bb * CC + c)) * NN + n) * DD + dbase;
#pragma unroll
        for (int g = 0; g < 4; g++) {
            int ccol = g * 32 + cb;
            f16x8_t hv, lv;
#pragma unroll
            for (int e = 0; e < 8; e++) {
                float vv = tr[rl * 132 + ccol + e];
                _Float16 h, l;
                split2(vv, h, l);
                hv[e] = h; lv[e] = l;
            }
            *(f16x8_t*)(dh + base + ccol) = hv;
            *(f16x8_t*)(dl + base + ccol) = lv;
        }
    }
}

// ---------------------------------------------------------------------------
// Kernel 2: per z: attn = (q @ k^T) * scale via 3-term fp16x2 MFMA,
// double-buffered LDS with next-tile prefetch. q,k carry a 16x scale each
// (from 16W), so scale = 0.0625/256. 1D grid of 2048, swizzled so all 64
// blocks of a z share one XCD (id%8).
// ---------------------------------------------------------------------------
__global__ __launch_bounds__(256) void gemm_qkt_mfma(
        const _Float16* __restrict__ qh, const _Float16* __restrict__ ql,
        const _Float16* __restrict__ kh, const _Float16* __restrict__ kl,
        float* __restrict__ attn) {
    __shared__ __align__(16) char smem[65536];
    _Float16* Ah0 = (_Float16*)smem;
    _Float16* Al0 = (_Float16*)(smem + 8192);
    _Float16* Bh0 = (_Float16*)(smem + 16384);
    _Float16* Bl0 = (_Float16*)(smem + 24576);
    _Float16* Ah1 = (_Float16*)(smem + 32768);
    _Float16* Al1 = (_Float16*)(smem + 40960);
    _Float16* Bh1 = (_Float16*)(smem + 49152);
    _Float16* Bl1 = (_Float16*)(smem + 57344);
    const int tid = threadIdx.x, lane = tid & 63, w = tid >> 6;
    const int wr = w >> 1, wc = w & 1;
    const int lm = lane & 15, quad = lane >> 4;
    const int id = blockIdx.x;
    const int rb8 = id & 7, qq = id >> 3;
    const int j = qq & 63, zhi = qq >> 6;
    const int z = zhi * 8 + rb8;
    const int row0 = (j >> 3) * 128, col0 = (j & 7) * 128;
    const size_t zo = (size_t)z * NN * DD;
    float* Cm = attn + (size_t)z * NN * NN;
    const int r_st = tid >> 2;
    const int c8 = (((tid & 3) ^ ((tid >> 3) & 3)) * 8);
    const int qx8 = ((quad ^ ((lm >> 1) & 3)) * 8);
    const float scale = 0.0625f / 256.0f;

    f32x4_t acc[4][4];
#pragma unroll
    for (int i = 0; i < 4; i++)
#pragma unroll
        for (int j2 = 0; j2 < 4; j2++) acc[i][j2] = (f32x4_t)(0.f);

    const _Float16* qhz = qh + zo;
    const _Float16* qlz = ql + zo;
    const _Float16* khz = kh + zo;
    const _Float16* klz = kl + zo;

    // prologue: stage k=0 into buf0
    STG(Ah0, qhz, row0, 0); STG(Al0, qlz, row0, 0);
    STG(Bh0, khz, col0, 0); STG(Bl0, klz, col0, 0);
    __syncthreads();
#pragma unroll
    for (int t = 0; t < 8; t += 2) {
        {   // even iter: compute buf0, prefetch (t+1) into buf1
            int kn = (t + 1) * 32;
            if (t + 1 < 8) {
                STG(Ah1, qhz, row0, kn); STG(Al1, qlz, row0, kn);
                STG(Bh1, khz, col0, kn); STG(Bl1, klz, col0, kn);
            }
            COMPUTE(Ah0, Al0, Bh0, Bl0);
            __syncthreads();
        }
        {   // odd iter: compute buf1, prefetch (t+2) into buf0
            int kn = (t + 2) * 32;
            if (t + 2 < 8) {
                STG(Ah0, qhz, row0, kn); STG(Al0, qlz, row0, kn);
                STG(Bh0, khz, col0, kn); STG(Bl0, klz, col0, kn);
            }
            COMPUTE(Ah1, Al1, Bh1, Bl1);
            __syncthreads();
        }
    }

#pragma unroll
    for (int mi = 0; mi < 4; mi++)
#pragma unroll
        for (int ni = 0; ni < 4; ni++) {
            int row = row0 + wr * 64 + mi * 16 + quad * 4;
            int col = col0 + wc * 64 + ni * 16 + lm;
#pragma unroll
            for (int r = 0; r < 4; r++)
                Cm[(size_t)(row + r) * NN + col] = acc[mi][ni][r] * scale;
        }
}

// ---------------------------------------------------------------------------
// Kernel 3: per (b,n): softmax stats for all 8 channels (no attn writeback),
// channel-summed probs -> top-16; writes ml, idx, cnt, countb; zeroes colsum.
// Wave-parallel: wave w owns channels 2w,2w+1 (all loads issued upfront,
// pure shfl_xor reductions, no barriers in stats); hierarchical top-16
// (per-wave quarter top-16 in regs, wave-0 merge). 3 barriers total.
// ---------------------------------------------------------------------------
__global__ __launch_bounds__(256) void softmax_topk(const float* __restrict__ attn,
                                                    float2* __restrict__ ml,
                                                    int* __restrict__ idx,
                                                    int* __restrict__ cnt,
                                                    int* __restrict__ countb,
                                                    float* __restrict__ colsum) {
    __shared__ float psum[4][NN];
    __shared__ float cval[64];
    __shared__ int   cidx[64];
    __shared__ int fsel[MAXSEL];
    __shared__ int fcnt;
    const int bn = blockIdx.x, b = bn >> 10, n = bn & 1023;
    const int tid = threadIdx.x, lane = tid & 63, w = tid >> 6;

    if (tid < CC) colsum[(size_t)(b * CC + tid) * NN + n] = 0.f;

    const int colb = lane * 16;
    // load both channels upfront: 8 float4 loads in flight, one latency hit
    float4 u[2][4];
#pragma unroll
    for (int p = 0; p < 2; p++) {
        const int c = w * 2 + p;
        const float* rowp = attn + (((size_t)(b * CC + c) * NN + n) * NN) + colb;
#pragma unroll
        for (int g = 0; g < 4; g++) u[p][g] = *(const float4*)(rowp + g * 4);
    }

    float acc[16];
#pragma unroll
    for (int e = 0; e < 16; e++) acc[e] = 0.f;

#pragma unroll
    for (int p = 0; p < 2; p++) {
        const int c = w * 2 + p;
        const float* f = (const float*)&u[p][0];
        float mx = f[0];
#pragma unroll
        for (int e = 1; e < 16; e++) mx = fmaxf(mx, f[e]);
#pragma unroll
        for (int off = 1; off < 64; off <<= 1) mx = fmaxf(mx, __shfl_xor(mx, off));
        float sm = 0.f;
        float pe[16];
#pragma unroll
        for (int e = 0; e < 16; e++) { pe[e] = expf(f[e] - mx); sm += pe[e]; }
#pragma unroll
        for (int off = 1; off < 64; off <<= 1) sm += __shfl_xor(sm, off);
        if (lane == 0) ml[(size_t)(b * CC + c) * NN + n] = make_float2(mx, sm);
        float inv = 1.0f / sm;
#pragma unroll
        for (int e = 0; e < 16; e++) acc[e] += pe[e] * inv;
    }
#pragma unroll
    for (int g = 0; g < 4; g++)
        *(float4*)&psum[w][colb + g * 4] =
            make_float4(acc[g * 4], acc[g * 4 + 1], acc[g * 4 + 2], acc[g * 4 + 3]);
    __syncthreads();

    // thread tid owns cols tid*4..+3 (== wave w's quarter [w*256,(w+1)*256))
    const int m4 = tid * 4;
    float4 a0 = *(const float4*)&psum[0][m4];
    float4 a1 = *(const float4*)&psum[1][m4];
    float4 a2 = *(const float4*)&psum[2][m4];
    float4 a3 = *(const float4*)&psum[3][m4];
    float v0 = a0.x + a1.x + a2.x + a3.x;
    float v1 = a0.y + a1.y + a2.y + a3.y;
    float v2 = a0.z + a1.z + a2.z + a3.z;
    float v3 = a0.w + a1.w + a2.w + a3.w;

    // per-wave top-16 of its quarter, all in regs (tie-break: lower index)
    float myv = 0.f; int myi = 0;
    for (int it = 0; it < KNBR; it++) {
        float bv = v0; int bi = m4;
        if (v1 > bv) { bv = v1; bi = m4 + 1; }
        if (v2 > bv) { bv = v2; bi = m4 + 2; }
        if (v3 > bv) { bv = v3; bi = m4 + 3; }
#pragma unroll
        for (int off = 1; off < 64; off <<= 1) {
            float ov = __shfl_xor(bv, off);
            int oi = __shfl_xor(bi, off);
            if (ov > bv || (ov == bv && oi < bi)) { bv = ov; bi = oi; }
        }
        if (lane == it) { myv = bv; myi = bi; }
        v0 = (bi == m4)     ? -INFINITY : v0;
        v1 = (bi == m4 + 1) ? -INFINITY : v1;
        v2 = (bi == m4 + 2) ? -INFINITY : v2;
        v3 = (bi == m4 + 3) ? -INFINITY : v3;
    }
    if (lane < KNBR) { cval[w * KNBR + lane] = myv; cidx[w * KNBR + lane] = myi; }
    __syncthreads();

    // wave 0: merge 4x16 candidates -> global top-16
    if (w == 0) {
        float mv = cval[lane]; int mi = cidx[lane];
        for (int it = 0; it < KNBR; it++) {
            float bv = mv; int bi = mi;
#pragma unroll
            for (int off = 1; off < 64; off <<= 1) {
                float ov = __shfl_xor(bv, off);
                int oi = __shfl_xor(bi, off);
                if (ov > bv || (ov == bv && oi < bi)) { bv = ov; bi = oi; }
            }
            if (lane == 0) fsel[it] = bi;
            if (mi == bi) mv = -INFINITY;
        }
        if (lane == 0) {
            bool has = false;
            for (int t = 0; t < KNBR; t++)
                if (fsel[t] == n) has = true;
            int c = KNBR;
            if (!has) { fsel[KNBR] = n; c = KNBR + 1; }
            fcnt = c;
            cnt[bn] = c;
        }
    }
    __syncthreads();
    if (tid < fcnt) {
        idx[bn * MAXSEL + tid] = fsel[tid];
        atomicAdd(&countb[b * NN + fsel[tid]], 1);
    }
}

// ---------------------------------------------------------------------------
// Kernel 4: per b: exclusive prefix scan of countb -> offb; init curs for
// the 8 z's of this b.
// ---------------------------------------------------------------------------
__global__ __launch_bounds__(256) void scan_offb(const int* __restrict__ countb,
                                                 int* __restrict__ offb,
                                                 int* __restrict__ curs) {
    __shared__ int wtot[4];
    const int b = blockIdx.x, tid = threadIdx.x, lane = tid & 63, w = tid >> 6;
    int c0 = countb[b * NN + tid * 4 + 0];
    int c1 = countb[b * NN + tid * 4 + 1];
    int c2 = countb[b * NN + tid * 4 + 2];
    int c3 = countb[b * NN + tid * 4 + 3];
    int tsum = c0 + c1 + c2 + c3;
    int incl = tsum;
#pragma unroll
    for (int off = 1; off < 64; off <<= 1) {
        int v = __shfl_up(incl, off);
        if (lane >= off) incl += v;
    }
    if (lane == 63) wtot[w] = incl;
    __syncthreads();
    int woff = 0;
    for (int i = 0; i < w; i++) woff += wtot[i];
    int base = woff + incl - tsum;
    int o0 = base, o1 = base + c0, o2 = base + c0 + c1, o3 = base + c0 + c1 + c2;
    offb[b * NN + tid * 4 + 0] = o0;
    offb[b * NN + tid * 4 + 1] = o1;
    offb[b * NN + tid * 4 + 2] = o2;
    offb[b * NN + tid * 4 + 3] = o3;
#pragma unroll
    for (int c = 0; c < CC; c++) {
        int z = b * CC + c;
        curs[z * NN + tid * 4 + 0] = o0;
        curs[z * NN + tid * 4 + 1] = o1;
        curs[z * NN + tid * 4 + 2] = o2;
        curs[z * NN + tid * 4 + 3] = o3;
    }
}

// ---------------------------------------------------------------------------
// Kernel 5 (merged rownorm + fill_csr): per (z,n) thread: recompute 17 masked
// probs from raw logits + (max,denom); row-normalize; accumulate colsum;
// append raw row-normalized values to CSR (colsum division deferred to
// out_sparse, so no dependency on complete colsum here).
// ---------------------------------------------------------------------------
__global__ __launch_bounds__(256) void rownorm_fill(const float* __restrict__ attn,
                                                    const float2* __restrict__ ml,
                                                    const int* __restrict__ idx,
                                                    const int* __restrict__ cnt,
                                                    int* __restrict__ curs,
                                                    float* __restrict__ nr,
                                                    float* __restrict__ colsum,
                                                    int* __restrict__ eidx,
                                                    float* __restrict__ eval) {
    const int t = blockIdx.x * 256 + threadIdx.x;  // z*N + n
    const int z = t >> 10, n = t & 1023;
    const int b = z >> 3;
    const int bn = b * NN + n;
    const int c_ = cnt[bn];
    const float* arow = attn + (size_t)t * NN;
    const float2 MM = ml[t];
    const float invl = 1.0f / MM.y;
    const size_t zb = (size_t)z * ZCAP;
    float a[MAXSEL];
    int kk[MAXSEL];
    float s = 0.f;
#pragma unroll
    for (int j = 0; j < MAXSEL; j++) {
        if (j < c_) {
            kk[j] = idx[bn * MAXSEL + j];
            float p = expf(arow[kk[j]] - MM.x) * invl;
            a[j] = p; s += p;
        }
    }
    const float inv = 1.f / (s + 1e-6f);
#pragma unroll
    for (int j = 0; j < MAXSEL; j++) {
        if (j < c_) {
            float v = a[j] * inv;
            nr[(size_t)t * MAXSEL + j] = v;
            atomicAdd(&colsum[(size_t)z * NN + kk[j]], v);
            int p = atomicAdd(&curs[z * NN + kk[j]], 1);
            eidx[zb + p] = n;
            eval[zb + p] = v;
        }
    }
}

// ---------------------------------------------------------------------------
// Kernel 6: out[z][n][:] = sum_j w_j/(colsum_j+eps) * sparse_col(k_j).
// One row (z,n) PER WAVE (4 rows/block, grid 8192): ~32 rows in flight per
// CU for latency hiding. Flat balanced gather: wave-scan prefix over the 17
// slice lengths, then each lane takes every-64th CSR entry (binary search
// over the 18-entry prefix) — hub columns no longer serialize on 15 threads.
// Non-temporal stores for the write-once 134 MB output.
// ---------------------------------------------------------------------------
__global__ __launch_bounds__(256) void out_sparse(const float* __restrict__ nr,
                                                  const int* __restrict__ idx,
                                                  const int* __restrict__ cnt,
                                                  const int* __restrict__ offb,
                                                  const int* __restrict__ countb,
                                                  const float* __restrict__ colsum,
                                                  const int* __restrict__ eidx,
                                                  const float* __restrict__ eval,
                                                  float* __restrict__ out) {
    __shared__ float row[4][NN];
    __shared__ float gscale[4][MAXSEL];
    __shared__ int   goff[4][MAXSEL];
    __shared__ int   gpref[4][MAXSEL + 1];
    const int tid = threadIdx.x, lane = tid & 63, w = tid >> 6;
    const int t = blockIdx.x * 4 + w;   // z*N + n, one row per wave
    const int z = t >> 10;
    const int b = z >> 3;
    const int bn = b * NN + (t & 1023);
    const size_t zb = (size_t)z * ZCAP;

    // zero this wave's row: 1024 floats = 256 float4, 4 per lane
    f32x4_t zz = (f32x4_t)(0.f);
#pragma unroll
    for (int q = 0; q < 4; q++) ((f32x4_t*)row[w])[q * 64 + lane] = zz;

    const int c_ = cnt[bn];
    float sc = 0.f;
    int off = 0, len = 0;
    if (lane < c_) {   // c_ <= MAXSEL <= 17 < 64
        int k = idx[bn * MAXSEL + lane];
        float wgt = nr[(size_t)t * MAXSEL + lane];
        sc = wgt / (colsum[(size_t)z * NN + k] + 1e-6f);
        off = offb[b * NN + k];
        len = countb[b * NN + k];
    }
    // wave-exclusive prefix over len (lanes >= c_ contribute 0)
    int incl = len;
#pragma unroll
    for (int o = 1; o < 32; o <<= 1) {
        int v = __shfl_up(incl, o);
        if (lane >= o) incl += v;
    }
    if (lane < MAXSEL) { gscale[w][lane] = sc; goff[w][lane] = off; }
    if (lane <= MAXSEL) gpref[w][lane] = incl - len;   // lane 17: total
    __syncthreads();

    const int tot = gpref[w][MAXSEL];
    for (int e = lane; e < tot; e += 64) {
        int lo = 0, hi = MAXSEL;
        while (hi - lo > 1) {
            int mid = (lo + hi) >> 1;
            if (gpref[w][mid] <= e) lo = mid; else hi = mid;
        }
        int i = e - gpref[w][lo] + goff[w][lo];
        int m = eidx[zb + i];
        float v = eval[zb + i];
        atomicAdd(&row[w][m], gscale[w][lo] * v);
    }
    __syncthreads();

    const size_t ob = (size_t)t * NN;
    f32x4_t* op = (f32x4_t*)(out + ob);
#pragma unroll
    for (int q = 0; q < 4; q++) {
        f32x4_t vo = ((f32x4_t*)row[w])[q * 64 + lane];
        __builtin_nontemporal_store(vo, op + q * 64 + lane);
    }
}

// ---------------------------------------------------------------------------
extern "C" void kernel_launch(void* const* d_in, const int* in_sizes, int n_in,
                              void* d_out, int out_size, void* d_ws, size_t ws_size,
                              hipStream_t stream) {
    const float* x = (const float*)d_in[0];    // [4,1024,256]
    const float* W = (const float*)d_in[1];    // [256,4096]
    float* out = (float*)d_out;                // [4,8,1024,1024]
    char* ws = (char*)d_ws;

    // attn (raw logits*scale) lives in d_out; dead before out_sparse writes.
    float* attn = (float*)d_out;

    // workspace layout (bytes)
    _Float16* qh  = (_Float16*)(ws);                    // 16 MB each
    _Float16* ql  = (_Float16*)(ws + 16777216ull);
    _Float16* kh  = (_Float16*)(ws + 33554432ull);
    _Float16* kl  = (_Float16*)(ws + 50331648ull);
    _Float16* xh  = (_Float16*)(ws + 67108864ull);      // 2 MB each
    _Float16* xl  = (_Float16*)(ws + 69206016ull);
    _Float16* wth = (_Float16*)(ws + 71303168ull);
    _Float16* wtl = (_Float16*)(ws + 73400320ull);
    int*    idx  = (int*)   (ws + 75497472ull);   // 278,528
    int*    cnt  = (int*)   (ws + 75776000ull);   // 16,384
    float*  nr   = (float*) (ws + 75792384ull);   // 2,228,224
    float*  colsum = (float*)(ws + 78020608ull);  // 131,072
    float2* ml   = (float2*)(ws + 78151680ull);   // 262,144
    int*    countb = (int*) (ws + 78413824ull);   // 16,384
    int*    offb = (int*)   (ws + 78430208ull);   // 16,384
    int*    curs = (int*)   (ws + 78446592ull);   // 131,072
    int*    eidx = (int*)   (ws + 78577664ull);   // 2,228,224
    float*  eval = (float*) (ws + 80805888ull);   // 2,228,224

    split_all<<<1280, 256, 0, stream>>>(x, W, xh, xl, wth, wtl, countb);
    gemm_xw_mfma<<<dim3(32, 32), 256, 0, stream>>>(xh, xl, wth, wtl,
                                                   qh, ql, kh, kl);
    gemm_qkt_mfma<<<2048, 256, 0, stream>>>(qh, ql, kh, kl, attn);
    softmax_topk<<<4096, 256, 0, stream>>>(attn, ml, idx, cnt, countb, colsum);
    scan_offb<<<4, 256, 0, stream>>>(countb, offb, curs);
    rownorm_fill<<<128, 256, 0, stream>>>(attn, ml, idx, cnt, curs, nr, colsum,
                                          eidx, eval);
    out_sparse<<<8192, 256, 0, stream>>>(nr, idx, cnt, offb, countb, colsum,
                                         eidx, eval, out);
}

// Round 6
// 389.186 us; speedup vs baseline: 1.0824x; 1.0824x over previous
//
#include <hip/hip_runtime.h>
#include <hip/hip_bf16.h>
#include <math.h>

// Problem constants
#define BB 4
#define NN 1024
#define DD 256
#define CC 8
#define KNBR 16
#define MAXSEL 17   // 16 top-k + possibly the diagonal
#define ZCAP (NN * MAXSEL)   // 17408 max CSR entries per z

typedef _Float16 f16x8_t __attribute__((ext_vector_type(8)));
typedef _Float16 f16x4_t __attribute__((ext_vector_type(4)));
typedef float    f32x4_t __attribute__((ext_vector_type(4)));

// async global->LDS, 16 bytes per lane. ldsbase must be wave-uniform
// (HW places lane i at ldsbase + i*16).
__device__ __forceinline__ void gl2lds16(const _Float16* g, _Float16* ldsbase) {
    __builtin_amdgcn_global_load_lds(
        (const __attribute__((address_space(1))) unsigned int*)g,
        (__attribute__((address_space(3))) unsigned int*)ldsbase, 16, 0, 0);
}

// 2-level fp16 split: v = h + l + eps, |eps| <= ~2^-23 |v|
__device__ __forceinline__ void split2(float v, _Float16& h, _Float16& l) {
    h = (_Float16)v;
    l = (_Float16)(v - (float)h);
}

// ---------------------------------------------------------------------------
// Kernel 0: fused input prep. Blocks 0..1023: split x (fp16 h+l).
// Blocks 1024..1279: transpose + split 16*W (scale keeps residuals out of
// fp16 subnormal range; compensated by qkt scale /256).
// Block 1024 also zeroes countb.
// ---------------------------------------------------------------------------
__global__ __launch_bounds__(256) void split_all(const float* __restrict__ x,
                                                 const float* __restrict__ W,
                                                 _Float16* __restrict__ xh,
                                                 _Float16* __restrict__ xl,
                                                 _Float16* __restrict__ Wth,
                                                 _Float16* __restrict__ Wtl,
                                                 int* __restrict__ countb) {
    const int tid = threadIdx.x;
    if (blockIdx.x < 1024) {
        int i = (blockIdx.x * 256 + tid) * 4;
        float4 v = *(const float4*)(x + i);
        f16x4_t hv, lv;
        _Float16 h, l;
        split2(v.x, h, l); hv[0] = h; lv[0] = l;
        split2(v.y, h, l); hv[1] = h; lv[1] = l;
        split2(v.z, h, l); hv[2] = h; lv[2] = l;
        split2(v.w, h, l); hv[3] = h; lv[3] = l;
        *(f16x4_t*)(xh + i) = hv;
        *(f16x4_t*)(xl + i) = lv;
    } else {
        const int b2 = blockIdx.x - 1024;
        if (b2 == 0) {
            int4 zz = make_int4(0, 0, 0, 0);
#pragma unroll
            for (int g = 0; g < 4; g++) ((int4*)countb)[tid + 256 * g] = zz;
        }
        __shared__ float t[64][65];
        const int n0 = (b2 & 63) * 64;
        const int k0 = (b2 >> 6) * 64;
#pragma unroll
        for (int i = 0; i < 16; i++) {
            int k = i * 4 + (tid >> 6);
            int n = tid & 63;
            t[k][n] = W[(size_t)(k0 + k) * 4096 + n0 + n];
        }
        __syncthreads();
#pragma unroll
        for (int i = 0; i < 16; i++) {
            int n = i * 4 + (tid >> 6);
            int k = tid & 63;
            _Float16 h, l;
            split2(t[k][n] * 16.f, h, l);
            size_t o = (size_t)(n0 + n) * 256 + k0 + k;
            Wth[o] = h; Wtl[o] = l;
        }
    }
}

// stage one 128x32 fp16 tile.
// LDS dest is linear (HW constraint of global_load_lds); the bank-conflict
// swizzle slot' = slot ^ ((row>>1)&3) is realized by pre-swizzling the
// GLOBAL source column (c8 is the swizzled column offset; row = r_st and
// r_st+64 share the same (row>>1)&3 so one c8 serves both halves).
#define STG(dst, src, rowbase, kk)                                             \
    do {                                                                       \
        gl2lds16((src) + (size_t)((rowbase) + r_st) * 256 + (kk) + c8,         \
                 &(dst)[(w * 64) * 8]);                                        \
        gl2lds16((src) + (size_t)((rowbase) + 64 + r_st) * 256 + (kk) + c8,    \
                 &(dst)[(256 + w * 64) * 8]);                                  \
    } while (0)

// 3-term product ladder (hh last). (ah+al)(bh+bl) ~ al*bh + ah*bl + ah*bh
#define MFMA3(accv, AH, AL, BH, BL)                                            \
    do {                                                                       \
        accv = __builtin_amdgcn_mfma_f32_16x16x32_f16(AL, BH, accv, 0, 0, 0);  \
        accv = __builtin_amdgcn_mfma_f32_16x16x32_f16(AH, BL, accv, 0, 0, 0);  \
        accv = __builtin_amdgcn_mfma_f32_16x16x32_f16(AH, BH, accv, 0, 0, 0);  \
    } while (0)

// fragment loads + MFMA for one staged K=32 tile set
#define COMPUTE(AH, AL, BH, BL)                                                \
    do {                                                                       \
        f16x8_t ah[4], al[4];                                                  \
        _Pragma("unroll")                                                      \
        for (int mi = 0; mi < 4; mi++) {                                       \
            int r = (wr * 64 + mi * 16 + lm) * 32 + qx8;                       \
            ah[mi] = *(const f16x8_t*)&(AH)[r];                                \
            al[mi] = *(const f16x8_t*)&(AL)[r];                                \
        }                                                                      \
        _Pragma("unroll")                                                      \
        for (int ni = 0; ni < 4; ni++) {                                       \
            int rb = (wc * 64 + ni * 16 + lm) * 32 + qx8;                      \
            f16x8_t bh = *(const f16x8_t*)&(BH)[rb];                           \
            f16x8_t bl = *(const f16x8_t*)&(BL)[rb];                           \
            _Pragma("unroll")                                                  \
            for (int mi = 0; mi < 4; mi++)                                     \
                MFMA3(acc[mi][ni], ah[mi], al[mi], bh, bl);                    \
        }                                                                      \
    } while (0)

// ---------------------------------------------------------------------------
// Kernel 1: qk = x @ (16W) via 3-term fp16x2 MFMA, double-buffered LDS with
// next-tile prefetch (one barrier per K-iter); LDS-transpose epilogue with
// coalesced fp16x8 stores of the 2-split q/k components.
// ---------------------------------------------------------------------------
__global__ __launch_bounds__(256) void gemm_xw_mfma(
        const _Float16* __restrict__ xh, const _Float16* __restrict__ xl,
        const _Float16* __restrict__ wth, const _Float16* __restrict__ wtl,
        _Float16* __restrict__ qh, _Float16* __restrict__ ql,
        _Float16* __restrict__ kh, _Float16* __restrict__ kl) {
    __shared__ __align__(16) char smem[65536];
    _Float16* Ah0 = (_Float16*)smem;
    _Float16* Al0 = (_Float16*)(smem + 8192);
    _Float16* Bh0 = (_Float16*)(smem + 16384);
    _Float16* Bl0 = (_Float16*)(smem + 24576);
    _Float16* Ah1 = (_Float16*)(smem + 32768);
    _Float16* Al1 = (_Float16*)(smem + 40960);
    _Float16* Bh1 = (_Float16*)(smem + 49152);
    _Float16* Bl1 = (_Float16*)(smem + 57344);
    const int tid = threadIdx.x, lane = tid & 63, w = tid >> 6;
    const int wr = w >> 1, wc = w & 1;
    const int lm = lane & 15, quad = lane >> 4;
    const int row0 = blockIdx.y * 128, col0 = blockIdx.x * 128;
    const int r_st = tid >> 2;
    // swizzled source column: slot (tid&3) XOR row-swizzle ((r_st>>1)&3)
    const int c8 = (((tid & 3) ^ ((tid >> 3) & 3)) * 8);
    // swizzled read slot for fragment loads (row-base contributes 0 mod 4)
    const int qx8 = ((quad ^ ((lm >> 1) & 3)) * 8);

    f32x4_t acc[4][4];
#pragma unroll
    for (int i = 0; i < 4; i++)
#pragma unroll
        for (int j = 0; j < 4; j++) acc[i][j] = (f32x4_t)(0.f);

    // prologue: stage k=0 into buf0
    STG(Ah0, xh, row0, 0); STG(Al0, xl, row0, 0);
    STG(Bh0, wth, col0, 0); STG(Bl0, wtl, col0, 0);
    __syncthreads();
#pragma unroll
    for (int t = 0; t < 8; t += 2) {
        {   // even iter: compute buf0, prefetch (t+1) into buf1
            int kn = (t + 1) * 32;
            if (t + 1 < 8) {
                STG(Ah1, xh, row0, kn); STG(Al1, xl, row0, kn);
                STG(Bh1, wth, col0, kn); STG(Bl1, wtl, col0, kn);
            }
            COMPUTE(Ah0, Al0, Bh0, Bl0);
            __syncthreads();
        }
        {   // odd iter: compute buf1, prefetch (t+2) into buf0
            int kn = (t + 2) * 32;
            if (t + 2 < 8) {
                STG(Ah0, xh, row0, kn); STG(Al0, xl, row0, kn);
                STG(Bh0, wth, col0, kn); STG(Bl0, wtl, col0, kn);
            }
            COMPUTE(Ah1, Al1, Bh1, Bl1);
            __syncthreads();
        }
    }

    // Epilogue: two 64-row passes through LDS (fp32, stride 132 = bank-safe),
    // then coalesced fp16x8 stores of the 2 split components.
    float* tr = (float*)smem;   // 64 x 132 fp32 = 33792 B
    const int s = col0 >> 11, c = (col0 >> 8) & 7, dbase = col0 & 255;
    _Float16* dh = s ? kh : qh;
    _Float16* dl = s ? kl : ql;
    const int rl = tid >> 2;
    const int cb = (tid & 3) * 8;
#pragma unroll
    for (int p = 0; p < 2; p++) {
        if (p) __syncthreads();
        if (wr == p) {
#pragma unroll
            for (int mi = 0; mi < 4; mi++) {
                int rloc = mi * 16 + quad * 4;
#pragma unroll
                for (int ni = 0; ni < 4; ni++) {
                    int cl = wc * 64 + ni * 16 + lm;
#pragma unroll
                    for (int r = 0; r < 4; r++)
                        tr[(rloc + r) * 132 + cl] = acc[mi][ni][r];
                }
            }
        }
        __syncthreads();
        int rr = row0 + p * 64 + rl;
        int bb = rr >> 10, n = rr & 1023;
        size_t base = (((size_t)(bb * CC + c)) * NN + n) * DD + dbase;
#pragma unroll
        for (int g = 0; g < 4; g++) {
            int ccol = g * 32 + cb;
            f16x8_t hv, lv;
#pragma unroll
            for (int e = 0; e < 8; e++) {
                float vv = tr[rl * 132 + ccol + e];
                _Float16 h, l;
                split2(vv, h, l);
                hv[e] = h; lv[e] = l;
            }
            *(f16x8_t*)(dh + base + ccol) = hv;
            *(f16x8_t*)(dl + base + ccol) = lv;
        }
    }
}

// ---------------------------------------------------------------------------
// Kernel 2: per z: attn = (q @ k^T) * scale via 3-term fp16x2 MFMA,
// double-buffered LDS with next-tile prefetch. q,k carry a 16x scale each
// (from 16W), so scale = 0.0625/256. 1D grid of 2048, swizzled so all 64
// blocks of a z share one XCD (id%8).
// ---------------------------------------------------------------------------
__global__ __launch_bounds__(256) void gemm_qkt_mfma(
        const _Float16* __restrict__ qh, const _Float16* __restrict__ ql,
        const _Float16* __restrict__ kh, const _Float16* __restrict__ kl,
        float* __restrict__ attn) {
    __shared__ __align__(16) char smem[65536];
    _Float16* Ah0 = (_Float16*)smem;
    _Float16* Al0 = (_Float16*)(smem + 8192);
    _Float16* Bh0 = (_Float16*)(smem + 16384);
    _Float16* Bl0 = (_Float16*)(smem + 24576);
    _Float16* Ah1 = (_Float16*)(smem + 32768);
    _Float16* Al1 = (_Float16*)(smem + 40960);
    _Float16* Bh1 = (_Float16*)(smem + 49152);
    _Float16* Bl1 = (_Float16*)(smem + 57344);
    const int tid = threadIdx.x, lane = tid & 63, w = tid >> 6;
    const int wr = w >> 1, wc = w & 1;
    const int lm = lane & 15, quad = lane >> 4;
    const int id = blockIdx.x;
    const int rb8 = id & 7, qq = id >> 3;
    const int j = qq & 63, zhi = qq >> 6;
    const int z = zhi * 8 + rb8;
    const int row0 = (j >> 3) * 128, col0 = (j & 7) * 128;
    const size_t zo = (size_t)z * NN * DD;
    float* Cm = attn + (size_t)z * NN * NN;
    const int r_st = tid >> 2;
    const int c8 = (((tid & 3) ^ ((tid >> 3) & 3)) * 8);
    const int qx8 = ((quad ^ ((lm >> 1) & 3)) * 8);
    const float scale = 0.0625f / 256.0f;

    f32x4_t acc[4][4];
#pragma unroll
    for (int i = 0; i < 4; i++)
#pragma unroll
        for (int j2 = 0; j2 < 4; j2++) acc[i][j2] = (f32x4_t)(0.f);

    const _Float16* qhz = qh + zo;
    const _Float16* qlz = ql + zo;
    const _Float16* khz = kh + zo;
    const _Float16* klz = kl + zo;

    // prologue: stage k=0 into buf0
    STG(Ah0, qhz, row0, 0); STG(Al0, qlz, row0, 0);
    STG(Bh0, khz, col0, 0); STG(Bl0, klz, col0, 0);
    __syncthreads();
#pragma unroll
    for (int t = 0; t < 8; t += 2) {
        {   // even iter: compute buf0, prefetch (t+1) into buf1
            int kn = (t + 1) * 32;
            if (t + 1 < 8) {
                STG(Ah1, qhz, row0, kn); STG(Al1, qlz, row0, kn);
                STG(Bh1, khz, col0, kn); STG(Bl1, klz, col0, kn);
            }
            COMPUTE(Ah0, Al0, Bh0, Bl0);
            __syncthreads();
        }
        {   // odd iter: compute buf1, prefetch (t+2) into buf0
            int kn = (t + 2) * 32;
            if (t + 2 < 8) {
                STG(Ah0, qhz, row0, kn); STG(Al0, qlz, row0, kn);
                STG(Bh0, khz, col0, kn); STG(Bl0, klz, col0, kn);
            }
            COMPUTE(Ah1, Al1, Bh1, Bl1);
            __syncthreads();
        }
    }

#pragma unroll
    for (int mi = 0; mi < 4; mi++)
#pragma unroll
        for (int ni = 0; ni < 4; ni++) {
            int row = row0 + wr * 64 + mi * 16 + quad * 4;
            int col = col0 + wc * 64 + ni * 16 + lm;
#pragma unroll
            for (int r = 0; r < 4; r++)
                Cm[(size_t)(row + r) * NN + col] = acc[mi][ni][r] * scale;
        }
}

// ---------------------------------------------------------------------------
// Kernel 3: per (b,n): softmax stats for all 8 channels + channel-summed
// probs -> top-16. Stats: wave w owns channels 2w,2w+1, pure shfl_xor
// reductions (no barriers). psum uses padded layout PHYS(c)=c+(c>>4)*4
// (20-word stride per 16 cols) so float4 writes at 64B lane stride hit all
// 32 banks. Top-16: wave 0 alone, by binary search on the uint bits of the
// 16th-largest value (positive floats compare as uints; ~31 iterations of
// 16x cmp+ballot+popcount, no dependent cross-lane shuffles), then exact
// set selection {v > V16} + lowest-index ties via one packed prefix scan.
// Matches jax.lax.top_k's value-then-lower-index selection set exactly.
// ---------------------------------------------------------------------------
__global__ __launch_bounds__(256) void softmax_topk(const float* __restrict__ attn,
                                                    float2* __restrict__ ml,
                                                    int* __restrict__ idx,
                                                    int* __restrict__ cnt,
                                                    int* __restrict__ countb,
                                                    float* __restrict__ colsum) {
    __shared__ float psum[4][1280];   // padded: 16 cols -> 20 words
    __shared__ int fsel[MAXSEL];
    __shared__ int fcnt;
    const int bn = blockIdx.x, b = bn >> 10, n = bn & 1023;
    const int tid = threadIdx.x, lane = tid & 63, w = tid >> 6;

    if (tid < CC) colsum[(size_t)(b * CC + tid) * NN + n] = 0.f;

    const int colb = lane * 16;   // logical col base
    const int pb   = lane * 20;   // physical (padded) col base
    // load both channels upfront: 8 float4 loads in flight, one latency hit
    float4 u[2][4];
#pragma unroll
    for (int p = 0; p < 2; p++) {
        const int c = w * 2 + p;
        const float* rowp = attn + (((size_t)(b * CC + c) * NN + n) * NN) + colb;
#pragma unroll
        for (int g = 0; g < 4; g++) u[p][g] = *(const float4*)(rowp + g * 4);
    }

    float acc[16];
#pragma unroll
    for (int e = 0; e < 16; e++) acc[e] = 0.f;

#pragma unroll
    for (int p = 0; p < 2; p++) {
        const int c = w * 2 + p;
        const float* f = (const float*)&u[p][0];
        float mx = f[0];
#pragma unroll
        for (int e = 1; e < 16; e++) mx = fmaxf(mx, f[e]);
#pragma unroll
        for (int off = 1; off < 64; off <<= 1) mx = fmaxf(mx, __shfl_xor(mx, off));
        float sm = 0.f;
        float pe[16];
#pragma unroll
        for (int e = 0; e < 16; e++) { pe[e] = expf(f[e] - mx); sm += pe[e]; }
#pragma unroll
        for (int off = 1; off < 64; off <<= 1) sm += __shfl_xor(sm, off);
        if (lane == 0) ml[(size_t)(b * CC + c) * NN + n] = make_float2(mx, sm);
        float inv = 1.0f / sm;
#pragma unroll
        for (int e = 0; e < 16; e++) acc[e] += pe[e] * inv;
    }
#pragma unroll
    for (int g = 0; g < 4; g++)
        *(float4*)&psum[w][pb + g * 4] =
            make_float4(acc[g * 4], acc[g * 4 + 1], acc[g * 4 + 2], acc[g * 4 + 3]);
    __syncthreads();

    // cross-wave channel sum: thread tid owns logical cols tid*4..+3
    const int p4 = tid * 4 + (tid >> 2) * 4;   // PHYS(tid*4)
    float4 a0 = *(const float4*)&psum[0][p4];
    float4 a1 = *(const float4*)&psum[1][p4];
    float4 a2 = *(const float4*)&psum[2][p4];
    float4 a3 = *(const float4*)&psum[3][p4];
    float4 vs;
    vs.x = a0.x + a1.x + a2.x + a3.x;
    vs.y = a0.y + a1.y + a2.y + a3.y;
    vs.z = a0.z + a1.z + a2.z + a3.z;
    vs.w = a0.w + a1.w + a2.w + a3.w;
    // write back into psum[0] (same location this thread read: no race)
    *(float4*)&psum[0][p4] = vs;
    __syncthreads();

    if (w == 0) {
        // lane owns logical cols lane*16..+15 of the summed row
        unsigned vb[16];
#pragma unroll
        for (int g = 0; g < 4; g++) {
            float4 t4 = *(const float4*)&psum[0][pb + g * 4];
            vb[g * 4 + 0] = __float_as_uint(t4.x);
            vb[g * 4 + 1] = __float_as_uint(t4.y);
            vb[g * 4 + 2] = __float_as_uint(t4.z);
            vb[g * 4 + 3] = __float_as_uint(t4.w);
        }
        // smallest u with count(v_bits > u) <= 15  ==  bits of 16th-largest
        unsigned lo = 0u, hi = 0x7F800000u;
        while (lo < hi) {
            unsigned mid = lo + ((hi - lo) >> 1);
            int c = 0;
#pragma unroll
            for (int e = 0; e < 16; e++)
                c += (int)__popcll(__ballot(vb[e] > mid));
            if (c <= 15) hi = mid; else lo = mid + 1;
        }
        const unsigned V = hi;
        int cgt = 0, ceq = 0;
#pragma unroll
        for (int e = 0; e < 16; e++) {
            cgt += (vb[e] > V) ? 1 : 0;
            ceq += (vb[e] == V) ? 1 : 0;
        }
        // packed wave prefix (gt in low 16 bits, eq in high 16)
        int pk = cgt | (ceq << 16);
        int incl = pk;
#pragma unroll
        for (int o = 1; o < 64; o <<= 1) {
            int v2 = __shfl_up(incl, o);
            if (lane >= o) incl += v2;
        }
        int tot = __shfl(incl, 63);
        int c1 = tot & 0xffff;          // total strictly-greater
        int need = KNBR - c1;           // ties to take (lowest index first)
        int excl = incl - pk;
        int pg = excl & 0xffff;
        int pe2 = excl >> 16;
        int lg = 0, le = 0;
#pragma unroll
        for (int e = 0; e < 16; e++) {
            if (vb[e] > V) {
                fsel[pg + lg] = colb + e; lg++;
            } else if (vb[e] == V) {
                if (pe2 + le < need) fsel[c1 + pe2 + le] = colb + e;
                le++;
            }
        }
        if (lane == 0) {
            bool has = false;
#pragma unroll
            for (int t2 = 0; t2 < KNBR; t2++)
                if (fsel[t2] == n) has = true;
            int c = KNBR;
            if (!has) { fsel[KNBR] = n; c = KNBR + 1; }
            fcnt = c;
            cnt[bn] = c;
        }
    }
    __syncthreads();
    if (tid < fcnt) {
        idx[bn * MAXSEL + tid] = fsel[tid];
        atomicAdd(&countb[b * NN + fsel[tid]], 1);
    }
}

// ---------------------------------------------------------------------------
// Kernel 4: per b: exclusive prefix scan of countb -> offb; init curs for
// the 8 z's of this b.
// ---------------------------------------------------------------------------
__global__ __launch_bounds__(256) void scan_offb(const int* __restrict__ countb,
                                                 int* __restrict__ offb,
                                                 int* __restrict__ curs) {
    __shared__ int wtot[4];
    const int b = blockIdx.x, tid = threadIdx.x, lane = tid & 63, w = tid >> 6;
    int c0 = countb[b * NN + tid * 4 + 0];
    int c1 = countb[b * NN + tid * 4 + 1];
    int c2 = countb[b * NN + tid * 4 + 2];
    int c3 = countb[b * NN + tid * 4 + 3];
    int tsum = c0 + c1 + c2 + c3;
    int incl = tsum;
#pragma unroll
    for (int off = 1; off < 64; off <<= 1) {
        int v = __shfl_up(incl, off);
        if (lane >= off) incl += v;
    }
    if (lane == 63) wtot[w] = incl;
    __syncthreads();
    int woff = 0;
    for (int i = 0; i < w; i++) woff += wtot[i];
    int base = woff + incl - tsum;
    int o0 = base, o1 = base + c0, o2 = base + c0 + c1, o3 = base + c0 + c1 + c2;
    offb[b * NN + tid * 4 + 0] = o0;
    offb[b * NN + tid * 4 + 1] = o1;
    offb[b * NN + tid * 4 + 2] = o2;
    offb[b * NN + tid * 4 + 3] = o3;
#pragma unroll
    for (int c = 0; c < CC; c++) {
        int z = b * CC + c;
        curs[z * NN + tid * 4 + 0] = o0;
        curs[z * NN + tid * 4 + 1] = o1;
        curs[z * NN + tid * 4 + 2] = o2;
        curs[z * NN + tid * 4 + 3] = o3;
    }
}

// ---------------------------------------------------------------------------
// Kernel 5 (merged rownorm + fill_csr): per (z,n) thread: recompute 17 masked
// probs from raw logits + (max,denom); row-normalize; accumulate colsum;
// append raw row-normalized values to CSR (colsum division deferred to
// out_sparse, so no dependency on complete colsum here).
// ---------------------------------------------------------------------------
__global__ __launch_bounds__(256) void rownorm_fill(const float* __restrict__ attn,
                                                    const float2* __restrict__ ml,
                                                    const int* __restrict__ idx,
                                                    const int* __restrict__ cnt,
                                                    int* __restrict__ curs,
                                                    float* __restrict__ nr,
                                                    float* __restrict__ colsum,
                                                    int* __restrict__ eidx,
                                                    float* __restrict__ eval) {
    const int t = blockIdx.x * 256 + threadIdx.x;  // z*N + n
    const int z = t >> 10, n = t & 1023;
    const int b = z >> 3;
    const int bn = b * NN + n;
    const int c_ = cnt[bn];
    const float* arow = attn + (size_t)t * NN;
    const float2 MM = ml[t];
    const float invl = 1.0f / MM.y;
    const size_t zb = (size_t)z * ZCAP;
    float a[MAXSEL];
    int kk[MAXSEL];
    float s = 0.f;
#pragma unroll
    for (int j = 0; j < MAXSEL; j++) {
        if (j < c_) {
            kk[j] = idx[bn * MAXSEL + j];
            float p = expf(arow[kk[j]] - MM.x) * invl;
            a[j] = p; s += p;
        }
    }
    const float inv = 1.f / (s + 1e-6f);
#pragma unroll
    for (int j = 0; j < MAXSEL; j++) {
        if (j < c_) {
            float v = a[j] * inv;
            nr[(size_t)t * MAXSEL + j] = v;
            atomicAdd(&colsum[(size_t)z * NN + kk[j]], v);
            int p = atomicAdd(&curs[z * NN + kk[j]], 1);
            eidx[zb + p] = n;
            eval[zb + p] = v;
        }
    }
}

// ---------------------------------------------------------------------------
// Kernel 6: out[z][n][:] = sum_j w_j/(colsum_j+eps) * sparse_col(k_j).
// One row (z,n) PER WAVE (4 rows/block, grid 8192): ~32 rows in flight per
// CU for latency hiding. Flat balanced gather: wave-scan prefix over the 17
// slice lengths, then each lane takes every-64th CSR entry (binary search
// over the 18-entry prefix) — hub columns no longer serialize on 15 threads.
// Plain stores (NT stores suspected of poisoning cross-iteration cache state
// on the aliased attn/out buffer — R5 A/B).
// ---------------------------------------------------------------------------
__global__ __launch_bounds__(256) void out_sparse(const float* __restrict__ nr,
                                                  const int* __restrict__ idx,
                                                  const int* __restrict__ cnt,
                                                  const int* __restrict__ offb,
                                                  const int* __restrict__ countb,
                                                  const float* __restrict__ colsum,
                                                  const int* __restrict__ eidx,
                                                  const float* __restrict__ eval,
                                                  float* __restrict__ out) {
    __shared__ float row[4][NN];
    __shared__ float gscale[4][MAXSEL];
    __shared__ int   goff[4][MAXSEL];
    __shared__ int   gpref[4][MAXSEL + 1];
    const int tid = threadIdx.x, lane = tid & 63, w = tid >> 6;
    const int t = blockIdx.x * 4 + w;   // z*N + n, one row per wave
    const int z = t >> 10;
    const int b = z >> 3;
    const int bn = b * NN + (t & 1023);
    const size_t zb = (size_t)z * ZCAP;

    // zero this wave's row: 1024 floats = 256 float4, 4 per lane
    f32x4_t zz = (f32x4_t)(0.f);
#pragma unroll
    for (int q = 0; q < 4; q++) ((f32x4_t*)row[w])[q * 64 + lane] = zz;

    const int c_ = cnt[bn];
    float sc = 0.f;
    int off = 0, len = 0;
    if (lane < c_) {   // c_ <= MAXSEL <= 17 < 64
        int k = idx[bn * MAXSEL + lane];
        float wgt = nr[(size_t)t * MAXSEL + lane];
        sc = wgt / (colsum[(size_t)z * NN + k] + 1e-6f);
        off = offb[b * NN + k];
        len = countb[b * NN + k];
    }
    // wave-exclusive prefix over len (lanes >= c_ contribute 0)
    int incl = len;
#pragma unroll
    for (int o = 1; o < 32; o <<= 1) {
        int v = __shfl_up(incl, o);
        if (lane >= o) incl += v;
    }
    if (lane < MAXSEL) { gscale[w][lane] = sc; goff[w][lane] = off; }
    if (lane <= MAXSEL) gpref[w][lane] = incl - len;   // lane 17: total
    __syncthreads();

    const int tot = gpref[w][MAXSEL];
    for (int e = lane; e < tot; e += 64) {
        int lo = 0, hi = MAXSEL;
        while (hi - lo > 1) {
            int mid = (lo + hi) >> 1;
            if (gpref[w][mid] <= e) lo = mid; else hi = mid;
        }
        int i = e - gpref[w][lo] + goff[w][lo];
        int m = eidx[zb + i];
        float v = eval[zb + i];
        atomicAdd(&row[w][m], gscale[w][lo] * v);
    }
    __syncthreads();

    const size_t ob = (size_t)t * NN;
    f32x4_t* op = (f32x4_t*)(out + ob);
#pragma unroll
    for (int q = 0; q < 4; q++) {
        op[q * 64 + lane] = ((f32x4_t*)row[w])[q * 64 + lane];
    }
}

// ---------------------------------------------------------------------------
extern "C" void kernel_launch(void* const* d_in, const int* in_sizes, int n_in,
                              void* d_out, int out_size, void* d_ws, size_t ws_size,
                              hipStream_t stream) {
    const float* x = (const float*)d_in[0];    // [4,1024,256]
    const float* W = (const float*)d_in[1];    // [256,4096]
    float* out = (float*)d_out;                // [4,8,1024,1024]
    char* ws = (char*)d_ws;

    // attn (raw logits*scale) lives in d_out; dead before out_sparse writes.
    float* attn = (float*)d_out;

    // workspace layout (bytes)
    _Float16* qh  = (_Float16*)(ws);                    // 16 MB each
    _Float16* ql  = (_Float16*)(ws + 16777216ull);
    _Float16* kh  = (_Float16*)(ws + 33554432ull);
    _Float16* kl  = (_Float16*)(ws + 50331648ull);
    _Float16* xh  = (_Float16*)(ws + 67108864ull);      // 2 MB each
    _Float16* xl  = (_Float16*)(ws + 69206016ull);
    _Float16* wth = (_Float16*)(ws + 71303168ull);
    _Float16* wtl = (_Float16*)(ws + 73400320ull);
    int*    idx  = (int*)   (ws + 75497472ull);   // 278,528
    int*    cnt  = (int*)   (ws + 75776000ull);   // 16,384
    float*  nr   = (float*) (ws + 75792384ull);   // 2,228,224
    float*  colsum = (float*)(ws + 78020608ull);  // 131,072
    float2* ml   = (float2*)(ws + 78151680ull);   // 262,144
    int*    countb = (int*) (ws + 78413824ull);   // 16,384
    int*    offb = (int*)   (ws + 78430208ull);   // 16,384
    int*    curs = (int*)   (ws + 78446592ull);   // 131,072
    int*    eidx = (int*)   (ws + 78577664ull);   // 2,228,224
    float*  eval = (float*) (ws + 80805888ull);   // 2,228,224

    split_all<<<1280, 256, 0, stream>>>(x, W, xh, xl, wth, wtl, countb);
    gemm_xw_mfma<<<dim3(32, 32), 256, 0, stream>>>(xh, xl, wth, wtl,
                                                   qh, ql, kh, kl);
    gemm_qkt_mfma<<<2048, 256, 0, stream>>>(qh, ql, kh, kl, attn);
    softmax_topk<<<4096, 256, 0, stream>>>(attn, ml, idx, cnt, countb, colsum);
    scan_offb<<<4, 256, 0, stream>>>(countb, offb, curs);
    rownorm_fill<<<128, 256, 0, stream>>>(attn, ml, idx, cnt, curs, nr, colsum,
                                          eidx, eval);
    out_sparse<<<8192, 256, 0, stream>>>(nr, idx, cnt, offb, countb, colsum,
                                         eidx, eval, out);
}